// Round 10
// baseline (79.811 us; speedup 1.0000x reference)
//
#include <hip/hip_runtime.h>

#define R_ 4
#define S_ 8
#define N_ 4096
#define D_ 64
#define KS_ 64               // K per stage
#define KH_ 2048             // K per block (half)
#define NST_ (KH_ / KS_)     // 32 stages
#define PART_ELEMS ((size_t)2 * R_ * N_ * D_)   // 8 MB fp32 partials

typedef __attribute__((ext_vector_type(8))) short bf16x8;
typedef __attribute__((ext_vector_type(4))) float f32x4;

__device__ __forceinline__ unsigned int f2bf(float f) {
    unsigned int u = __float_as_uint(f);
    return (u + 0x7FFFu + ((u >> 16) & 1u)) >> 16;   // RNE to bf16
}

// Kernel 1: ycombT[r][o][k] = bf16( coef[r] * sum_d x[r][k][d] * fc_w[r][o][d] )
__global__ __launch_bounds__(256) void prep_kernel(
    const float* __restrict__ theta, const float* __restrict__ tt,
    const float* __restrict__ x, const float* __restrict__ fc_w,
    unsigned short* __restrict__ ycombT) {
    int r  = blockIdx.x >> 6;
    int kb = blockIdx.x & 63;
    int tid = threadIdx.x;

    __shared__ float xs[64][64];
    __shared__ float ws[64][65];

    const float* xp = x    + ((size_t)r * N_ + (size_t)kb * 64) * D_;
    const float* wp = fc_w + (size_t)r * D_ * D_;
    for (int i = 0; i < 16; ++i) {
        int flat = i * 256 + tid;
        xs[flat >> 6][flat & 63] = xp[flat];
        ws[flat >> 6][flat & 63] = wp[flat];
    }
    float coef = 0.f;
#pragma unroll
    for (int s = 0; s < S_; ++s) coef += theta[r * S_ + s] * tt[r * S_ + s];
    __syncthreads();

    int o = tid & 63, kg = tid >> 6;
    for (int kl = kg; kl < 64; kl += 4) {
        float dot = 0.f;
#pragma unroll
        for (int d = 0; d < D_; ++d) dot += xs[kl][d] * ws[o][d];
        ycombT[(size_t)(r * D_ + o) * N_ + (size_t)kb * 64 + kl] =
            (unsigned short)f2bf(coef * dot);
    }
}

// Kernel 2: block = (r, K-half q, 128-row group). 8 waves x 16 rows.
// Dense A staging (R9-proven: 4 rows x 256B per inst), B shared by the whole
// block (67 MB total). Both tiles XOR-swizzled, double-buffered (48 KB).
// Writes fp32 partials part[q][r][n][d]; no in-block K-reduction.
__global__ __launch_bounds__(512, 4) void gemm_kernel(
    const float* __restrict__ a, const unsigned short* __restrict__ ycombT,
    float* __restrict__ part) {
    int bid = blockIdx.x;             // 256 blocks
    int r   = bid & 3;
    int q   = (bid >> 2) & 1;         // K half
    int rg  = bid >> 3;               // 0..31, 128-row group
    int tid  = threadIdx.x;
    int wave = tid >> 6;              // 8 waves, 16 rows each
    int lane = tid & 63;
    int l15  = lane & 15;
    int kg   = lane >> 4;

    // pool: [A0:16K][A1:16K][B0:8K][B1:8K] ; A tile [128][64] bf16, B [64][64]
    __shared__ __align__(16) char pool[49152];
#define ABASE(buf) ((buf) * 16384)
#define BBASE(buf) (32768 + (buf) * 8192)

    // ---- A staging: thread t covers rows (t>>4)+32j (j=0..3), floats (t&15)*4.
    // Per inst a wave reads 4 rows x 256B dense.
    int arow0 = tid >> 4;              // 0..31
    int ak    = (tid & 15) * 4;
    int agran = (tid & 15) >> 1;       // 16B granule (0..7)
    int ahalf = tid & 1;
    int swzA  = arow0 & 7;             // row&7 is j-independent (32j = 0 mod 8)
    const float* asrc = a + ((size_t)(r * N_ + rg * 128)) * N_ + (size_t)q * KH_;

    // ---- B staging: thread t -> o-row tid>>3, granule tid&7 (16B = 8 bf16)
    int brow = tid >> 3, bg = tid & 7;
    const unsigned short* ysrc = ycombT + (size_t)(r * D_ + brow) * N_
                                 + (size_t)q * KH_ + bg * 8;
    int bslot = (bg ^ (brow & 7)) << 4;

    f32x4 acc0 = {0.f, 0.f, 0.f, 0.f};
    f32x4 acc1 = {0.f, 0.f, 0.f, 0.f};
    f32x4 acc2 = {0.f, 0.f, 0.f, 0.f};
    f32x4 acc3 = {0.f, 0.f, 0.f, 0.f};

    float4 an[4];
    uint4  bv;

    auto loadA = [&](int s) {
#pragma unroll
        for (int j = 0; j < 4; ++j)
            an[j] = *(const float4*)(asrc + (size_t)(arow0 + 32 * j) * N_
                                          + (size_t)s * KS_ + ak);
    };
    auto loadB = [&](int s) {
        bv = *(const uint4*)(ysrc + (size_t)s * KS_);
    };
    auto writeA = [&](int buf) {
#pragma unroll
        for (int j = 0; j < 4; ++j) {
            int row = arow0 + 32 * j;
            uint2 p;
            p.x = (f2bf(an[j].y) << 16) | f2bf(an[j].x);
            p.y = (f2bf(an[j].w) << 16) | f2bf(an[j].z);
            *(uint2*)(pool + ABASE(buf) + row * 128
                      + ((agran ^ swzA) << 4) + (ahalf << 3)) = p;
        }
    };
    auto writeB = [&](int buf) {
        *(uint4*)(pool + BBASE(buf) + brow * 128 + bslot) = bv;
    };
    auto compute = [&](int buf) {
#pragma unroll
        for (int ks = 0; ks < 2; ++ks) {
            int slot = ((ks * 4 + kg) ^ (l15 & 7)) << 4;
            bf16x8 af = *(const bf16x8*)(pool + ABASE(buf) + (wave * 16 + l15) * 128 + slot);
            bf16x8 b0 = *(const bf16x8*)(pool + BBASE(buf) + ( 0 + l15) * 128 + slot);
            bf16x8 b1 = *(const bf16x8*)(pool + BBASE(buf) + (16 + l15) * 128 + slot);
            bf16x8 b2 = *(const bf16x8*)(pool + BBASE(buf) + (32 + l15) * 128 + slot);
            bf16x8 b3 = *(const bf16x8*)(pool + BBASE(buf) + (48 + l15) * 128 + slot);
            acc0 = __builtin_amdgcn_mfma_f32_16x16x32_bf16(af, b0, acc0, 0, 0, 0);
            acc1 = __builtin_amdgcn_mfma_f32_16x16x32_bf16(af, b1, acc1, 0, 0, 0);
            acc2 = __builtin_amdgcn_mfma_f32_16x16x32_bf16(af, b2, acc2, 0, 0, 0);
            acc3 = __builtin_amdgcn_mfma_f32_16x16x32_bf16(af, b3, acc3, 0, 0, 0);
        }
    };

    // prologue: stage 0 -> LDS buf0; stage 1 raw -> regs
    loadA(0); loadB(0);
    writeA(0); writeB(0);
    loadA(1); loadB(1);
    __syncthreads();

#pragma unroll 2
    for (int s = 0; s < NST_; ++s) {
        int buf = s & 1;
        compute(buf);
        __syncthreads();                       // all reads of buf done
        if (s + 1 < NST_) {
            writeA(buf ^ 1); writeB(buf ^ 1);  // stage s+1 into other buffer
            if (s + 2 < NST_) { loadA(s + 2); loadB(s + 2); }
            __syncthreads();                   // writes visible before next compute
        }
    }

    // direct partial write. C/D layout: col=c*16+l15, rloc=kg*4+j (m89).
    float* pb = part + (((size_t)(q * R_ + r) * N_) + rg * 128 + wave * 16) * D_;
#pragma unroll
    for (int c = 0; c < 4; ++c) {
        f32x4 acc = (c == 0) ? acc0 : (c == 1) ? acc1 : (c == 2) ? acc2 : acc3;
#pragma unroll
        for (int j = 0; j < 4; ++j)
            pb[(size_t)(kg * 4 + j) * D_ + c * 16 + l15] = acc[j];
    }
}

// Kernel 3: combine partials -> bias+PReLU (diffusions) -> 1x1 conv+PReLU (latent)
__global__ __launch_bounds__(256) void combine_kernel(
    const float* __restrict__ part, const float* __restrict__ fc_b,
    const float* __restrict__ conv_w, const float* __restrict__ conv_b,
    const float* __restrict__ alpha0p, const float* __restrict__ alpha1p,
    float* __restrict__ out) {
    const size_t nd = (size_t)N_ * D_;
    const size_t diff_off = (size_t)R_ * nd;
    size_t i = ((size_t)blockIdx.x * 256 + threadIdx.x) * 4;
    int col0 = (int)(i & 63);
    const float alpha0 = *alpha0p, alpha1 = *alpha1p;

    float4 diff[4];
#pragma unroll
    for (int r = 0; r < R_; ++r) {
        float4 p0 = *(const float4*)(part + (size_t)(0 * R_ + r) * nd + i);
        float4 p1 = *(const float4*)(part + (size_t)(1 * R_ + r) * nd + i);
        float4 b  = *(const float4*)(fc_b + r * D_ + col0);
        float4 s;
        s.x = p0.x + p1.x + b.x;
        s.y = p0.y + p1.y + b.y;
        s.z = p0.z + p1.z + b.z;
        s.w = p0.w + p1.w + b.w;
        s.x = (s.x >= 0.f) ? s.x : alpha0 * s.x;
        s.y = (s.y >= 0.f) ? s.y : alpha0 * s.y;
        s.z = (s.z >= 0.f) ? s.z : alpha0 * s.z;
        s.w = (s.w >= 0.f) ? s.w : alpha0 * s.w;
        diff[r] = s;
        *(float4*)(out + diff_off + r * nd + i) = s;
    }
#pragma unroll
    for (int sx = 0; sx < R_; ++sx) {
        float w0 = conv_w[sx * R_ + 0], w1 = conv_w[sx * R_ + 1];
        float w2 = conv_w[sx * R_ + 2], w3 = conv_w[sx * R_ + 3];
        float cb = conv_b[sx];
        float4 v;
        v.x = cb + w0 * diff[0].x + w1 * diff[1].x + w2 * diff[2].x + w3 * diff[3].x;
        v.y = cb + w0 * diff[0].y + w1 * diff[1].y + w2 * diff[2].y + w3 * diff[3].y;
        v.z = cb + w0 * diff[0].z + w1 * diff[1].z + w2 * diff[2].z + w3 * diff[3].z;
        v.w = cb + w0 * diff[0].w + w1 * diff[1].w + w2 * diff[2].w + w3 * diff[3].w;
        v.x = (v.x >= 0.f) ? v.x : alpha1 * v.x;
        v.y = (v.y >= 0.f) ? v.y : alpha1 * v.y;
        v.z = (v.z >= 0.f) ? v.z : alpha1 * v.z;
        v.w = (v.w >= 0.f) ? v.w : alpha1 * v.w;
        *(float4*)(out + sx * nd + i) = v;
    }
}

extern "C" void kernel_launch(void* const* d_in, const int* in_sizes, int n_in,
                              void* d_out, int out_size, void* d_ws, size_t ws_size,
                              hipStream_t stream) {
    const float* theta  = (const float*)d_in[0];
    const float* tt     = (const float*)d_in[1];
    const float* a      = (const float*)d_in[2];
    const float* x      = (const float*)d_in[3];
    const float* fc_w   = (const float*)d_in[4];
    const float* fc_b   = (const float*)d_in[5];
    const float* conv_w = (const float*)d_in[6];
    const float* conv_b = (const float*)d_in[7];
    const float* alpha0 = (const float*)d_in[8];
    const float* alpha1 = (const float*)d_in[9];
    float* out = (float*)d_out;

    float* part = (float*)d_ws;                                       // 8 MiB fp32
    unsigned short* ycombT =
        (unsigned short*)((char*)d_ws + PART_ELEMS * sizeof(float));  // 2 MiB bf16

    prep_kernel<<<dim3(R_ * (N_ / 64)), dim3(256), 0, stream>>>(theta, tt, x, fc_w, ycombT);
    gemm_kernel<<<dim3(256), dim3(512), 0, stream>>>(a, ycombT, part);
    combine_kernel<<<dim3((N_ * D_) / 4 / 256), dim3(256), 0, stream>>>(
        part, fc_b, conv_w, conv_b, alpha0, alpha1, out);
}

// Round 11
// 64.279 us; speedup vs baseline: 1.2416x; 1.2416x over previous
//
#include <hip/hip_runtime.h>

#define R_ 4
#define S_ 8
#define N_ 4096
#define D_ 64
#define KS_ 128              // K per stage
#define KH_ 2048             // K per block (half)
#define NST_ (KH_ / KS_)     // 16 stages
#define PART_ELEMS ((size_t)2 * R_ * N_ * D_)   // 8 MB fp32 partials

typedef __attribute__((ext_vector_type(8))) short bf16x8;
typedef __attribute__((ext_vector_type(4))) float f32x4;

__device__ __forceinline__ unsigned int f2bf(float f) {
    unsigned int u = __float_as_uint(f);
    return (u + 0x7FFFu + ((u >> 16) & 1u)) >> 16;   // RNE to bf16
}

// Kernel 1: ycombT[r][o][k] = bf16( coef[r] * sum_d x[r][k][d] * fc_w[r][o][d] )
__global__ __launch_bounds__(256) void prep_kernel(
    const float* __restrict__ theta, const float* __restrict__ tt,
    const float* __restrict__ x, const float* __restrict__ fc_w,
    unsigned short* __restrict__ ycombT) {
    int r  = blockIdx.x >> 6;
    int kb = blockIdx.x & 63;
    int tid = threadIdx.x;

    __shared__ float xs[64][64];
    __shared__ float ws[64][65];

    const float* xp = x    + ((size_t)r * N_ + (size_t)kb * 64) * D_;
    const float* wp = fc_w + (size_t)r * D_ * D_;
    for (int i = 0; i < 16; ++i) {
        int flat = i * 256 + tid;
        xs[flat >> 6][flat & 63] = xp[flat];
        ws[flat >> 6][flat & 63] = wp[flat];
    }
    float coef = 0.f;
#pragma unroll
    for (int s = 0; s < S_; ++s) coef += theta[r * S_ + s] * tt[r * S_ + s];
    __syncthreads();

    int o = tid & 63, kg = tid >> 6;
    for (int kl = kg; kl < 64; kl += 4) {
        float dot = 0.f;
#pragma unroll
        for (int d = 0; d < D_; ++d) dot += xs[kl][d] * ws[o][d];
        ycombT[(size_t)(r * D_ + o) * N_ + (size_t)kb * 64 + kl] =
            (unsigned short)f2bf(coef * dot);
    }
}

// Kernel 2: block = (r, K-half q, 128-row group). 8 waves x 16 rows, KS=128.
// R9's exact pipeline (dense 2-row x 512B A bursts, XOR swizzle, 2 barriers
// per stage, reg prefetch 2 ahead) but BM=128 (B traffic halved to 64 MB) and
// SINGLE 48 KB LDS buffer (writes sit between the barriers anyway).
// Writes fp32 partials part[q][r][n][d].
__global__ __launch_bounds__(512) void gemm_kernel(
    const float* __restrict__ a, const unsigned short* __restrict__ ycombT,
    float* __restrict__ part) {
    int bid = blockIdx.x;             // 256 blocks
    int r   = bid & 3;
    int q   = (bid >> 2) & 1;         // K half
    int rg  = bid >> 3;               // 0..31, 128-row group
    int tid  = threadIdx.x;
    int wave = tid >> 6;              // 8 waves, 16 rows each
    int lane = tid & 63;
    int l15  = lane & 15;
    int kg   = lane >> 4;

    // pool: [A: 128 rows x 256B = 32KB][B: 64 rows x 256B = 16KB]
    __shared__ __align__(16) char pool[49152];
#define BBASE 32768

    // ---- A staging: thread covers rows (16j + tr), j=0..7, tr=tid>>5;
    // floats (tid&31)*4. Per inst: wave = 2 rows x 512B dense (R9 pattern).
    int tr    = tid >> 5;              // 0..15
    int ak    = (tid & 31) * 4;        // float offset in 128-wide stage tile
    int agran = (tid & 31) >> 1;       // 16B granule (0..15)
    int ahalf = tid & 1;
    int swzA  = (tr & 7) << 1;         // row&7 = tr&7 (16j = 0 mod 8)
    const float* asrc = a + ((size_t)(r * N_ + rg * 128)) * N_ + (size_t)q * KH_;

    // ---- B staging (R9 map): thread -> o-row tid>>3, granules g2,g2+1 (16B)
    int srow = tid >> 3, g2 = (tid & 7) * 2;
    int swzB = (srow & 7) << 1;
    const unsigned short* ysrc = ycombT + (size_t)(r * D_ + srow) * N_
                                 + (size_t)q * KH_ + g2 * 8;

    int swzr = (l15 & 7) << 1;         // read-side XOR (same for A and B)

    f32x4 acc0 = {0.f, 0.f, 0.f, 0.f};
    f32x4 acc1 = {0.f, 0.f, 0.f, 0.f};
    f32x4 acc2 = {0.f, 0.f, 0.f, 0.f};
    f32x4 acc3 = {0.f, 0.f, 0.f, 0.f};

    float4 an[8];
    uint4  bv0, bv1;

    auto loadA = [&](int s) {
#pragma unroll
        for (int j = 0; j < 8; ++j)
            an[j] = *(const float4*)(asrc + (size_t)(16 * j + tr) * N_
                                          + (size_t)s * KS_ + ak);
    };
    auto loadB = [&](int s) {
        bv0 = *(const uint4*)(ysrc + (size_t)s * KS_);
        bv1 = *(const uint4*)(ysrc + (size_t)s * KS_ + 8);
    };
    auto writeA = [&]() {
#pragma unroll
        for (int j = 0; j < 8; ++j) {
            int row = 16 * j + tr;
            uint2 p;
            p.x = (f2bf(an[j].y) << 16) | f2bf(an[j].x);
            p.y = (f2bf(an[j].w) << 16) | f2bf(an[j].z);
            *(uint2*)(pool + row * 256 + ((agran ^ swzA) << 4) + (ahalf << 3)) = p;
        }
    };
    auto writeB = [&]() {
        *(uint4*)(pool + BBASE + srow * 256 + (((g2    ) ^ swzB) << 4)) = bv0;
        *(uint4*)(pool + BBASE + srow * 256 + (((g2 + 1) ^ swzB) << 4)) = bv1;
    };
    auto compute = [&]() {
#pragma unroll
        for (int st = 0; st < 4; ++st) {
            int slot = ((st * 4 + kg) ^ swzr) << 4;
            bf16x8 af = *(const bf16x8*)(pool + (wave * 16 + l15) * 256 + slot);
            bf16x8 b0 = *(const bf16x8*)(pool + BBASE + ( 0 + l15) * 256 + slot);
            bf16x8 b1 = *(const bf16x8*)(pool + BBASE + (16 + l15) * 256 + slot);
            bf16x8 b2 = *(const bf16x8*)(pool + BBASE + (32 + l15) * 256 + slot);
            bf16x8 b3 = *(const bf16x8*)(pool + BBASE + (48 + l15) * 256 + slot);
            acc0 = __builtin_amdgcn_mfma_f32_16x16x32_bf16(af, b0, acc0, 0, 0, 0);
            acc1 = __builtin_amdgcn_mfma_f32_16x16x32_bf16(af, b1, acc1, 0, 0, 0);
            acc2 = __builtin_amdgcn_mfma_f32_16x16x32_bf16(af, b2, acc2, 0, 0, 0);
            acc3 = __builtin_amdgcn_mfma_f32_16x16x32_bf16(af, b3, acc3, 0, 0, 0);
        }
    };

    // prologue: stage 0 -> LDS; stage 1 raw -> regs
    loadA(0); loadB(0);
    writeA(); writeB();
    loadA(1); loadB(1);
    __syncthreads();

    for (int s = 0; s < NST_; ++s) {
        compute();
        __syncthreads();                 // all reads of the buffer done
        if (s + 1 < NST_) {
            writeA(); writeB();          // stage s+1 into the (single) buffer
            if (s + 2 < NST_) { loadA(s + 2); loadB(s + 2); }
            __syncthreads();             // writes visible before next compute
        }
    }

    // partial write. C/D layout: col=c*16+l15, rloc=kg*4+j (m89).
    float* pb = part + (((size_t)(q * R_ + r) * N_) + rg * 128 + wave * 16) * D_;
#pragma unroll
    for (int c = 0; c < 4; ++c) {
        f32x4 acc = (c == 0) ? acc0 : (c == 1) ? acc1 : (c == 2) ? acc2 : acc3;
#pragma unroll
        for (int j = 0; j < 4; ++j)
            pb[(size_t)(kg * 4 + j) * D_ + c * 16 + l15] = acc[j];
    }
}

// Kernel 3: combine partials -> bias+PReLU (diffusions) -> 1x1 conv+PReLU (latent)
__global__ __launch_bounds__(256) void combine_kernel(
    const float* __restrict__ part, const float* __restrict__ fc_b,
    const float* __restrict__ conv_w, const float* __restrict__ conv_b,
    const float* __restrict__ alpha0p, const float* __restrict__ alpha1p,
    float* __restrict__ out) {
    const size_t nd = (size_t)N_ * D_;
    const size_t diff_off = (size_t)R_ * nd;
    size_t i = ((size_t)blockIdx.x * 256 + threadIdx.x) * 4;
    int col0 = (int)(i & 63);
    const float alpha0 = *alpha0p, alpha1 = *alpha1p;

    float4 diff[4];
#pragma unroll
    for (int r = 0; r < R_; ++r) {
        float4 p0 = *(const float4*)(part + (size_t)(0 * R_ + r) * nd + i);
        float4 p1 = *(const float4*)(part + (size_t)(1 * R_ + r) * nd + i);
        float4 b  = *(const float4*)(fc_b + r * D_ + col0);
        float4 s;
        s.x = p0.x + p1.x + b.x;
        s.y = p0.y + p1.y + b.y;
        s.z = p0.z + p1.z + b.z;
        s.w = p0.w + p1.w + b.w;
        s.x = (s.x >= 0.f) ? s.x : alpha0 * s.x;
        s.y = (s.y >= 0.f) ? s.y : alpha0 * s.y;
        s.z = (s.z >= 0.f) ? s.z : alpha0 * s.z;
        s.w = (s.w >= 0.f) ? s.w : alpha0 * s.w;
        diff[r] = s;
        *(float4*)(out + diff_off + r * nd + i) = s;
    }
#pragma unroll
    for (int sx = 0; sx < R_; ++sx) {
        float w0 = conv_w[sx * R_ + 0], w1 = conv_w[sx * R_ + 1];
        float w2 = conv_w[sx * R_ + 2], w3 = conv_w[sx * R_ + 3];
        float cb = conv_b[sx];
        float4 v;
        v.x = cb + w0 * diff[0].x + w1 * diff[1].x + w2 * diff[2].x + w3 * diff[3].x;
        v.y = cb + w0 * diff[0].y + w1 * diff[1].y + w2 * diff[2].y + w3 * diff[3].y;
        v.z = cb + w0 * diff[0].z + w1 * diff[1].z + w2 * diff[2].z + w3 * diff[3].z;
        v.w = cb + w0 * diff[0].w + w1 * diff[1].w + w2 * diff[2].w + w3 * diff[3].w;
        v.x = (v.x >= 0.f) ? v.x : alpha1 * v.x;
        v.y = (v.y >= 0.f) ? v.y : alpha1 * v.y;
        v.z = (v.z >= 0.f) ? v.z : alpha1 * v.z;
        v.w = (v.w >= 0.f) ? v.w : alpha1 * v.w;
        *(float4*)(out + sx * nd + i) = v;
    }
}

extern "C" void kernel_launch(void* const* d_in, const int* in_sizes, int n_in,
                              void* d_out, int out_size, void* d_ws, size_t ws_size,
                              hipStream_t stream) {
    const float* theta  = (const float*)d_in[0];
    const float* tt     = (const float*)d_in[1];
    const float* a      = (const float*)d_in[2];
    const float* x      = (const float*)d_in[3];
    const float* fc_w   = (const float*)d_in[4];
    const float* fc_b   = (const float*)d_in[5];
    const float* conv_w = (const float*)d_in[6];
    const float* conv_b = (const float*)d_in[7];
    const float* alpha0 = (const float*)d_in[8];
    const float* alpha1 = (const float*)d_in[9];
    float* out = (float*)d_out;

    float* part = (float*)d_ws;                                       // 8 MiB fp32
    unsigned short* ycombT =
        (unsigned short*)((char*)d_ws + PART_ELEMS * sizeof(float));  // 2 MiB bf16

    prep_kernel<<<dim3(R_ * (N_ / 64)), dim3(256), 0, stream>>>(theta, tt, x, fc_w, ycombT);
    gemm_kernel<<<dim3(256), dim3(512), 0, stream>>>(a, ycombT, part);
    combine_kernel<<<dim3((N_ * D_) / 4 / 256), dim3(256), 0, stream>>>(
        part, fc_b, conv_w, conv_b, alpha0, alpha1, out);
}